// Round 14
// baseline (421.923 us; speedup 1.0000x reference)
//
#include <hip/hip_runtime.h>

typedef unsigned short u16;
typedef unsigned int u32;
typedef __bf16 bf16x8 __attribute__((ext_vector_type(8)));
typedef float f32x4 __attribute__((ext_vector_type(4)));
typedef u32 u32x4 __attribute__((ext_vector_type(4)));

#define MFMA(a,b,c) __builtin_amdgcn_mfma_f32_16x16x32_bf16((a),(b),(c),0,0,0)

#define BB 4
#define NN 4096
#define DD 1024
#define HH 16
#define HDIM 64
#define RR 256
#define NBH 64
#define KSP 8   // k2a splits

__device__ __forceinline__ float bf2f(u16 h){
  union { u32 u; float f; } c; c.u = ((u32)h) << 16; return c.f;
}
__device__ __forceinline__ u16 f2bf(float f){
  union { float f; u32 u; } c; c.f = f;
  u32 u = c.u;
  return (u16)((u + 0x7FFFu + ((u >> 16) & 1u)) >> 16);
}
__device__ __forceinline__ f32x4 zero4(){ f32x4 v = {0.f,0.f,0.f,0.f}; return v; }

// async global->LDS, 16B per lane; LDS dest = wave-uniform base + lane*16
__device__ __forceinline__ void gload16(const void* g, void* l) {
  __builtin_amdgcn_global_load_lds(
      (const __attribute__((address_space(1))) void*)g,
      (__attribute__((address_space(3))) void*)l, 16, 0, 0);
}

// ---------------- prep kernels ----------------

// x (16384 x 1024 f32) -> x2 (16384 x 2048 bf16): row = [hi | lo]
__global__ void split_cast_x2_kernel(const float4* __restrict__ src, u16* __restrict__ x2, int n4)
{
  int i = blockIdx.x * blockDim.x + threadIdx.x;
  int stride = gridDim.x * blockDim.x;
  for (; i < n4; i += stride) {
    float4 v = src[i];
    int m = i >> 8;          // 256 float4 per 1024-row
    int k4 = (i & 255) * 4;
    ushort4 h, lo;
    h.x = f2bf(v.x); lo.x = f2bf(v.x - bf2f(h.x));
    h.y = f2bf(v.y); lo.y = f2bf(v.y - bf2f(h.y));
    h.z = f2bf(v.z); lo.z = f2bf(v.z - bf2f(h.z));
    h.w = f2bf(v.w); lo.w = f2bf(v.w - bf2f(h.w));
    *(ushort4*)&x2[(size_t)m * 2048 + k4] = h;
    *(ushort4*)&x2[(size_t)m * 2048 + 1024 + k4] = lo;
  }
}

// projection split: natural (for k2b) + row-permuted (for k2a)
// phi_a[32k+8lq+4h+j] = P[32k+16h+4lq+j]  (so kvt columns match k2b's register layout)
__global__ void split_cast_proj_kernel(const float4* __restrict__ src,
                                       ushort4* __restrict__ hi, ushort4* __restrict__ lo,
                                       u16* __restrict__ hia, u16* __restrict__ loa)
{
  int i = blockIdx.x * blockDim.x + threadIdx.x;
  if (i >= 4096) return;   // 16384 elems / 4
  float4 v = src[i];
  ushort4 h, l4;
  h.x = f2bf(v.x); l4.x = f2bf(v.x - bf2f(h.x));
  h.y = f2bf(v.y); l4.y = f2bf(v.y - bf2f(h.y));
  h.z = f2bf(v.z); l4.z = f2bf(v.z - bf2f(h.z));
  h.w = f2bf(v.w); l4.w = f2bf(v.w - bf2f(h.w));
  hi[i] = h;
  lo[i] = l4;
  int prow = i >> 4;          // source row (16 float4 per 64-col row)
  int c4 = (i & 15) * 4;
  int drow = (prow & ~31) | (((prow >> 2) & 3) << 3) | (((prow >> 4) & 1) << 2) | (prow & 3);
  *(ushort4*)&hia[drow * 64 + c4] = h;
  *(ushort4*)&loa[drow * 64 + c4] = l4;
}

// w_qkv (1024 x 3072) -> w2qk (2048 x 2048, row n = [w^T_n | w^T_n]) and wv (1024 x 1024 = w^T v-cols)
__global__ void transpose_wqkv_kernel(const float* __restrict__ src,
                                      u16* __restrict__ w2qk, u16* __restrict__ wv)
{
  __shared__ float T[32][33];
  const int c0 = blockIdx.x * 32, r0 = blockIdx.y * 32;
  const int t = threadIdx.x;
  #pragma unroll
  for (int i = 0; i < 4; ++i) {
    int r = t >> 3, c = (t & 7) + i * 8;
    T[r][c] = src[(size_t)(r0 + r) * 3072 + c0 + c];
  }
  __syncthreads();
  #pragma unroll
  for (int i = 0; i < 4; ++i) {
    int r = t >> 3, c = (t & 7) + i * 8;
    float v = T[c][r];
    int orow = c0 + r, ocol = r0 + c;
    u16 h = f2bf(v);
    if (orow < 2048) {
      w2qk[(size_t)orow * 2048 + ocol] = h;
      w2qk[(size_t)orow * 2048 + 1024 + ocol] = h;
    } else {
      wv[(size_t)(orow - 2048) * 1024 + ocol] = h;
    }
  }
}

// w_proj (1024x1024) -> wpt (transposed bf16)
__global__ void transpose_kernel(const float* __restrict__ src, u16* __restrict__ dst)
{
  __shared__ float T[32][33];
  const int c0 = blockIdx.x * 32, r0 = blockIdx.y * 32;
  const int t = threadIdx.x;
  #pragma unroll
  for (int i = 0; i < 4; ++i) {
    int r = t >> 3, c = (t & 7) + i * 8;
    T[r][c] = src[(size_t)(r0 + r) * 1024 + c0 + c];
  }
  __syncthreads();
  #pragma unroll
  for (int i = 0; i < 4; ++i) {
    int r = t >> 3, c = (t & 7) + i * 8;
    dst[(size_t)(c0 + r) * 1024 + r0 + c] = f2bf(T[c][r]);
  }
}

// ---------------- 128x128 pipelined GEMM (m97/m103 structure) ----------------
// A: M x K row-major (lda), B: N x K row-major (ldb). 4 waves (2m x 2n), BK=32,
// 32 KiB LDS dbuf -> ~4 blocks/CU co-resident (cross-block overlap hides barrier
// drains; learn_hip m103: 912 TF vs 792 for 256^2 at this structure; our 256^2
// BK64 measured 860). Counted vmcnt(4). Swizzle: R10-proven g(r)=(r>>1)&3 on 64B
// rows, both sides (measured 0 bank conflicts).
// MODE 0: qk hi/lo scatter; MODE 1: v scatter; MODE 2: f32 + bias.
template<int MODE>
__launch_bounds__(256, 4)
__global__ void gemm128_kernel(const u16* __restrict__ A, const u16* __restrict__ B,
                               const int K, const int lda, const int ldb,
                               u16* __restrict__ o0, u16* __restrict__ o1,
                               u16* __restrict__ o2, u16* __restrict__ o3,
                               float* __restrict__ fout, const float* __restrict__ bias)
{
  __shared__ __align__(16) u16 lds[2][2][128 * 32];   // [buf][A/B][row*32+col], 32 KiB
  const int t = threadIdx.x;
  const int w = t >> 6, l = t & 63;
  const int m0 = blockIdx.x * 128, n0 = blockIdx.y * 128;
  const int wm = w & 1, wn = w >> 1;           // 2 x 2 wave grid
  const int lr = l & 15, lq = l >> 4;          // frag row / k-quarter

  f32x4 acc[4][4];
  #pragma unroll
  for (int m = 0; m < 4; ++m)
    #pragma unroll
    for (int n = 0; n < 4; ++n) acc[m][n] = zero4();

  const int nt = K / 32;

  // stage tile kt (128 rows x 32 cols per matrix) into buffer bi.
  // chunk = 16 rows x 32 cols = 1 KiB = one gload16 per wave; 2 chunks/wave/matrix.
  // Dest linear (l*16B); source col block pre-swizzled with g(row)=(row>>1)&3
  // = (l>>3)&3 (chunk base rows are multiples of 16 -> row-group independent).
  auto stage = [&](int kt, int bi) {
    const int srow = l >> 2;
    const int scol = kt * 32 + (((l & 3) ^ ((l >> 3) & 3)) << 3);
    #pragma unroll
    for (int i = 0; i < 2; ++i) {
      const int c = w * 2 + i;
      gload16(&A[(size_t)(m0 + c * 16 + srow) * lda + scol], &lds[bi][0][c * 512 + l * 8]);
    }
    #pragma unroll
    for (int i = 0; i < 2; ++i) {
      const int c = w * 2 + i;
      gload16(&B[(size_t)(n0 + c * 16 + srow) * ldb + scol], &lds[bi][1][c * 512 + l * 8]);
    }
  };

  stage(0, 0);
  stage(1, 1);
  asm volatile("s_waitcnt vmcnt(4)" ::: "memory");   // tile 0 landed (per wave)
  __builtin_amdgcn_s_barrier();
  __builtin_amdgcn_sched_barrier(0);

  for (int kt = 0; kt < nt; ++kt) {
    const int bi = kt & 1;
    const u16* la = &lds[bi][0][0];
    const u16* lb = &lds[bi][1][0];
    const int sw = (lq ^ ((lr >> 1) & 3)) << 4;   // read-side block xor (bytes)
    bf16x8 a[4], b[4];
    #pragma unroll
    for (int m = 0; m < 4; ++m)
      a[m] = *(const bf16x8*)((const char*)la + (wm*64 + m*16 + lr)*64 + sw);
    #pragma unroll
    for (int n = 0; n < 4; ++n)
      b[n] = *(const bf16x8*)((const char*)lb + (wn*64 + n*16 + lr)*64 + sw);
    asm volatile("s_waitcnt lgkmcnt(0)" ::: "memory");  // all our LDS reads in regs
    __builtin_amdgcn_s_barrier();                       // all waves done reading buf bi
    __builtin_amdgcn_sched_barrier(0);
    if (kt + 2 < nt) stage(kt + 2, bi);                 // refill freed buffer
    __builtin_amdgcn_s_setprio(1);
    #pragma unroll
    for (int m = 0; m < 4; ++m)
      #pragma unroll
      for (int n = 0; n < 4; ++n)
        acc[m][n] = MFMA(a[m], b[n], acc[m][n]);        // overlaps stage issue
    __builtin_amdgcn_s_setprio(0);
    if (kt + 2 < nt)      { asm volatile("s_waitcnt vmcnt(4)" ::: "memory"); }
    else if (kt + 1 < nt) { asm volatile("s_waitcnt vmcnt(0)" ::: "memory"); }
    __builtin_amdgcn_s_barrier();                       // tile kt+1 ready for all
    __builtin_amdgcn_sched_barrier(0);
  }

  // epilogue
  #pragma unroll
  for (int m = 0; m < 4; ++m)
    #pragma unroll
    for (int n = 0; n < 4; ++n)
      #pragma unroll
      for (int j = 0; j < 4; ++j) {
        int gm = m0 + wm*64 + m*16 + lq*4 + j;
        int gc = n0 + wn*64 + n*16 + lr;
        float v = acc[m][n][j];
        if (MODE == 2) {
          fout[(size_t)gm * 1024 + gc] = v + bias[gc];
        } else {
          int hh = (gc >> 6) & 15, hd = gc & 63;
          int b2 = gm >> 12, tok = gm & 4095;
          size_t idx = ((size_t)(b2 * HH + hh) * NN + tok) * HDIM + hd;
          if (MODE == 0) {
            u16 hi = f2bf(v), lo = f2bf(v - bf2f(hi));
            if ((gc >> 10) == 0) { o0[idx] = hi; o1[idx] = lo; }
            else                 { o2[idx] = hi; o3[idx] = lo; }
          } else {
            o0[idx] = f2bf(v);
          }
        }
      }
}

// ---------------- K2a (R11 v1, measured-best): k features + kv via Kft ----------------
// grid (bh=64, split=KSP), 256 threads. kv_ext = Kf^T @ [V | 1 | 0..] (N=80).
// Uses the PERMUTED projection (phi_a/plo_a) so kvt columns are in k2b's order.
// R12's register-resident variant regressed (-29us): holding pb frags + kvacc +
// facc through the loop cost more than the Kft LDS round-trip saves. Reverted.
__launch_bounds__(256)
__global__ void k2a_kernel(const u16* __restrict__ khi, const u16* __restrict__ klo,
                           const u16* __restrict__ vb,
                           const u16* __restrict__ phi, const u16* __restrict__ plo,
                           float* __restrict__ kvpart)
{
  __shared__ __align__(16) u16 Kh[32*72];
  __shared__ __align__(16) u16 Kl[32*72];
  __shared__ __align__(16) u16 Kft[256*40];
  __shared__ __align__(16) u16 Vt[80*40];
  __shared__ float xnorm[32];
  const int bh = blockIdx.x, sp = blockIdx.y;
  const int t = threadIdx.x, w = t >> 6, l = t & 63;
  const int lr = l & 15, lk = (l >> 4) * 8, l4 = (l >> 4) * 4;
  const size_t base = (size_t)bh * NN * HDIM;
  f32x4 kvacc[4][5];
  #pragma unroll
  for (int i = 0; i < 4; ++i)
    #pragma unroll
    for (int j = 0; j < 5; ++j) kvacc[i][j] = zero4();

  const int TILES = (NN / KSP) / 32;
  for (int tile = 0; tile < TILES; ++tile) {
    const int nb = sp * (NN / KSP) + tile * 32;
    __syncthreads();  // prev iter done reading LDS
    {
      int row = t >> 3, c8 = (t & 7) * 8;
      size_t g = base + (size_t)(nb + row) * HDIM + c8;
      uint4 khv = *(const uint4*)&khi[g];
      uint4 klv = *(const uint4*)&klo[g];
      *(uint4*)&Kh[row*72 + c8] = khv;
      *(uint4*)&Kl[row*72 + c8] = klv;
      uint4 vv = *(const uint4*)&vb[g];
      const u16* pv = (const u16*)&vv;
      #pragma unroll
      for (int j = 0; j < 8; ++j) Vt[(c8 + j)*40 + row] = pv[j];
      if (t < 32) {
        Vt[64*40 + t] = 0x3F80u;  // ones column -> k_sum
        #pragma unroll
        for (int d = 65; d < 80; ++d) Vt[d*40 + t] = 0;
      }
      // parallel xnorm from staging regs: 8 lanes per row
      const u16* ph = (const u16*)&khv;
      const u16* pl = (const u16*)&klv;
      float s = 0.f;
      #pragma unroll
      for (int j = 0; j < 8; ++j) {
        float qv = bf2f(ph[j]) + bf2f(pl[j]);
        s += qv * qv;
      }
      s += __shfl_xor(s, 1);
      s += __shfl_xor(s, 2);
      s += __shfl_xor(s, 4);
      if ((t & 7) == 0) xnorm[row] = 0.5f * s;
    }
    __syncthreads();
    // feature GEMM: M=32 rows, wave w owns r-cols [64w, 64w+64)
    f32x4 facc[2][4];
    #pragma unroll
    for (int i = 0; i < 2; ++i)
      #pragma unroll
      for (int j = 0; j < 4; ++j) facc[i][j] = zero4();
    #pragma unroll
    for (int ks = 0; ks < 2; ++ks) {
      bf16x8 ah[2], al[2];
      #pragma unroll
      for (int fm = 0; fm < 2; ++fm) {
        ah[fm] = *(const bf16x8*)&Kh[(fm*16 + lr)*72 + ks*32 + lk];
        al[fm] = *(const bf16x8*)&Kl[(fm*16 + lr)*72 + ks*32 + lk];
      }
      #pragma unroll
      for (int fn = 0; fn < 4; ++fn) {
        int r = w*64 + fn*16 + lr;
        bf16x8 pbh = *(const bf16x8*)&phi[r*HDIM + ks*32 + lk];
        bf16x8 pbl = *(const bf16x8*)&plo[r*HDIM + ks*32 + lk];
        #pragma unroll
        for (int fm = 0; fm < 2; ++fm) {
          facc[fm][fn] = MFMA(al[fm], pbh, facc[fm][fn]);
          facc[fm][fn] = MFMA(ah[fm], pbl, facc[fm][fn]);
          facc[fm][fn] = MFMA(ah[fm], pbh, facc[fm][fn]);
        }
      }
    }
    #pragma unroll
    for (int fm = 0; fm < 2; ++fm)
      #pragma unroll
      for (int fn = 0; fn < 4; ++fn)
        #pragma unroll
        for (int j = 0; j < 4; ++j) {
          int row = fm*16 + l4 + j;          // n local
          int r = w*64 + fn*16 + lr;
          float e = __expf(facc[fm][fn][j] - xnorm[row]) * 0.0625f + 1e-6f;
          Kft[r*40 + row] = f2bf(e);
        }
    __syncthreads();
    // kv accumulate: wave w owns r-rows [64w, 64w+64), K=32 (this tile)
    {
      bf16x8 bv[5];
      #pragma unroll
      for (int fn = 0; fn < 5; ++fn)
        bv[fn] = *(const bf16x8*)&Vt[(fn*16 + lr)*40 + lk];
      #pragma unroll
      for (int fr = 0; fr < 4; ++fr) {
        bf16x8 a = *(const bf16x8*)&Kft[(w*64 + fr*16 + lr)*40 + lk];
        #pragma unroll
        for (int fn = 0; fn < 5; ++fn) kvacc[fr][fn] = MFMA(a, bv[fn], kvacc[fr][fn]);
      }
    }
  }
  // kvpart[bh][sp][d][r]
  #pragma unroll
  for (int fr = 0; fr < 4; ++fr)
    #pragma unroll
    for (int fn = 0; fn < 5; ++fn)
      #pragma unroll
      for (int j = 0; j < 4; ++j) {
        int r = w*64 + fr*16 + l4 + j;
        int d = fn*16 + lr;
        kvpart[(((size_t)bh*KSP + sp)*80 + d)*256 + r] = kvacc[fr][fn][j];
      }
}

__global__ void kv_reduce_kernel(const float* __restrict__ kvpart, u16* __restrict__ kvt)
{
  int i = blockIdx.x * 256 + threadIdx.x;
  if (i >= NBH * 80 * 256) return;
  int bh = i / (80 * 256), rem = i - bh * (80 * 256);
  float s = 0.f;
  #pragma unroll
  for (int sp = 0; sp < KSP; ++sp)
    s += kvpart[((size_t)bh*KSP + sp)*80*256 + rem];
  kvt[i] = f2bf(s);  // kvt[bh][d][r], d<64: kv^T; d==64: k_sum
}

// ---------------- K2b v7: fused per-slot feature+PV, PINNED schedule ----------------
// Same algebra/layout as v6 (all operands LDS-staged). The slot loop and tile
// loop are NOT unrolled and each slot ends with sched_barrier(0): full unroll
// exposed 96 independent loads, scheduler hoisted them, regalloc spilled ~220
// dwords/lane (R4-R7's ~650MB excess traffic). Pinning fixed it (R8: -77µs).
__launch_bounds__(512, 2)
__global__ void k2b_kernel(const u16* __restrict__ qhi, const u16* __restrict__ qlo,
                           const u16* __restrict__ kvt,
                           const u16* __restrict__ phi, const u16* __restrict__ plo,
                           u16* __restrict__ attn)
{
  __shared__ __align__(16) u16 KV[80*256];    // [d][r] 512B rows; 16B-blk ^= d&7
  __shared__ __align__(16) u16 PH[256*64];    // [fr][d] 128B rows; 16B-blk ^= fr&7
  __shared__ __align__(16) u16 PL[256*64];
  const int bh = blockIdx.x, b = bh >> 4, h = bh & 15;
  const int c0 = blockIdx.y * 512;
  const int t = threadIdx.x, w = t >> 6, l = t & 63;
  const int lr = l & 15, lq = l >> 4;
  const size_t base = (size_t)bh * NN * HDIM;

  // stage kv_ext (80x256) + projection (256x64 hi/lo), both-sides swizzle
  {
    const uint4* kvg = (const uint4*)(kvt + (size_t)bh * 80 * 256);
    #pragma unroll
    for (int i = 0; i < 5; ++i) {
      int idx = t + i * 512;
      int d = idx >> 5, rb = idx & 31;
      *(uint4*)((char*)KV + d * 512 + ((rb ^ (d & 7)) << 4)) = kvg[idx];
    }
    const uint4* pg = (const uint4*)phi;
    const uint4* lg = (const uint4*)plo;
    #pragma unroll
    for (int i = 0; i < 4; ++i) {
      int idx = t + i * 512;
      int fr = idx >> 3, sl = idx & 7;
      int off = fr * 128 + (((sl ^ (fr & 7))) << 4);
      *(uint4*)((char*)PH + off) = pg[idx];
      *(uint4*)((char*)PL + off) = lg[idx];
    }
  }
  __syncthreads();

  const int swl = (lr & 7) << 4;       // projection read-side row xor (bytes)
  #pragma unroll 1
  for (int tile = 0; tile < 4; ++tile) {
    const int r0 = c0 + tile * 128 + w * 16;
    // Q frags (B-operand: col=lr -> q-row = r0+lr, k = d = half*32 + lq*8 + e)
    bf16x8 ah0, ah1, al0, al1;
    {
      size_t g = base + (size_t)(r0 + lr) * HDIM + lq*8;
      ah0 = *(const bf16x8*)&qhi[g];
      al0 = *(const bf16x8*)&qlo[g];
      ah1 = *(const bf16x8*)&qhi[g + 32];
      al1 = *(const bf16x8*)&qlo[g + 32];
    }
    // xnorm for q-row r0+lr: per-lane partial over d, reduce across lq groups
    float s = 0.f;
    #pragma unroll
    for (int e = 0; e < 8; ++e) {
      float q0 = (float)ah0[e] + (float)al0[e];
      float q1 = (float)ah1[e] + (float)al1[e];
      s += q0 * q0 + q1 * q1;
    }
    s += __shfl_xor(s, 16);
    s += __shfl_xor(s, 32);
    const float xn = 0.5f * s;

    f32x4 oa0 = zero4(), oa1 = zero4(), oa2 = zero4(), oa3 = zero4(), oa4 = zero4();

    // fused slots: feature frags fn=2i,2i+1 -> exp -> PV slot i.
    // NOT unrolled + sched_barrier: loads of slot i+1 cannot be hoisted into slot i.
    #pragma unroll 1
    for (int i = 0; i < 8; ++i) {
      f32x4 f0 = zero4(), f1 = zero4();
      {
        const int ro0 = (32*i + lr) * 128;     // PH/PL byte row for fn=2i
        const int ro1 = ro0 + 2048;            // fn=2i+1 (+16 rows)
        const int cb0 = (lq*16) ^ swl;         // k-half 0 (cols 0..31)
        const int cb1 = (64 + lq*16) ^ swl;    // k-half 1 (cols 32..63)
        bf16x8 v;
        v = *(const bf16x8*)((const char*)PH + ro0 + cb0);
        f0 = MFMA(v, ah0, f0); f0 = MFMA(v, al0, f0);
        v = *(const bf16x8*)((const char*)PL + ro0 + cb0);
        f0 = MFMA(v, ah0, f0);
        v = *(const bf16x8*)((const char*)PH + ro0 + cb1);
        f0 = MFMA(v, ah1, f0); f0 = MFMA(v, al1, f0);
        v = *(const bf16x8*)((const char*)PL + ro0 + cb1);
        f0 = MFMA(v, ah1, f0);
        v = *(const bf16x8*)((const char*)PH + ro1 + cb0);
        f1 = MFMA(v, ah0, f1); f1 = MFMA(v, al0, f1);
        v = *(const bf16x8*)((const char*)PL + ro1 + cb0);
        f1 = MFMA(v, ah0, f1);
        v = *(const bf16x8*)((const char*)PH + ro1 + cb1);
        f1 = MFMA(v, ah1, f1); f1 = MFMA(v, al1, f1);
        v = *(const bf16x8*)((const char*)PL + ro1 + cb1);
        f1 = MFMA(v, ah1, f1);
      }
      // exp + pack -> PV A-frag (k = i*32 + lq*8 + e), register-only value
      u32x4 aw;
      aw.x = (u32)f2bf(__expf(f0[0] - xn) * 0.0625f + 1e-6f)
           | ((u32)f2bf(__expf(f0[1] - xn) * 0.0625f + 1e-6f) << 16);
      aw.y = (u32)f2bf(__expf(f0[2] - xn) * 0.0625f + 1e-6f)
           | ((u32)f2bf(__expf(f0[3] - xn) * 0.0625f + 1e-6f) << 16);
      aw.z = (u32)f2bf(__expf(f1[0] - xn) * 0.0625f + 1e-6f)
           | ((u32)f2bf(__expf(f1[1] - xn) * 0.0625f + 1e-6f) << 16);
      aw.w = (u32)f2bf(__expf(f1[2] - xn) * 0.0625f + 1e-6f)
           | ((u32)f2bf(__expf(f1[3] - xn) * 0.0625f + 1e-6f) << 16);
      bf16x8 a = __builtin_bit_cast(bf16x8, aw);
      // PV: KV rows d=fn*16+lr; (d&7)==(lr&7) for all fn
      const int kvsw = (((i << 2) | lq) ^ (lr & 7)) << 4;
      oa0 = MFMA(a, *(const bf16x8*)((const char*)KV + (0*16+lr)*512 + kvsw), oa0);
      oa1 = MFMA(a, *(const bf16x8*)((const char*)KV + (1*16+lr)*512 + kvsw), oa1);
      oa2 = MFMA(a, *(const bf16x8*)((const char*)KV + (2*16+lr)*512 + kvsw), oa2);
      oa3 = MFMA(a, *(const bf16x8*)((const char*)KV + (3*16+lr)*512 + kvsw), oa3);
      oa4 = MFMA(a, *(const bf16x8*)((const char*)KV + (4*16+lr)*512 + kvsw), oa4);
      __builtin_amdgcn_sched_barrier(0);   // pin: no cross-slot motion
    }
    // normalize (denom = col 64 -> lane lr==0 within each lq) + store
    #pragma unroll
    for (int j = 0; j < 4; ++j) {
      float dn = __shfl(oa4[j], l & 48) + 1e-6f;
      float inv = 1.0f / dn;
      int q = r0 + lq*4 + j;
      u16* arow = attn + ((size_t)b * NN + q) * DD + h * HDIM + lr;
      arow[0]  = f2bf(oa0[j] * inv);
      arow[16] = f2bf(oa1[j] * inv);
      arow[32] = f2bf(oa2[j] * inv);
      arow[48] = f2bf(oa3[j] * inv);
    }
  }
}

// ---------------- host ----------------

extern "C" void kernel_launch(void* const* d_in, const int* in_sizes, int n_in,
                              void* d_out, int out_size, void* d_ws, size_t ws_size,
                              hipStream_t stream)
{
  const float* x      = (const float*)d_in[0];
  const float* w_qkv  = (const float*)d_in[1];
  const float* w_proj = (const float*)d_in[2];
  const float* b_proj = (const float*)d_in[3];
  const float* proj   = (const float*)d_in[4];
  float* out = (float*)d_out;

  char* p = (char*)d_ws;
  auto alloc = [&](size_t nbytes) {
    char* r = p; p += (nbytes + 255) & ~(size_t)255; return r;
  };
  const size_t NE = (size_t)16777216;  // B*N*D elements
  u16* x2    = (u16*)alloc(NE * 2 * 2);                 // 16384 x 2048 (hi|lo)
  u16* w2qk  = (u16*)alloc((size_t)2048 * 2048 * 2);    // duplicated qk weights
  u16* wv    = (u16*)alloc((size_t)1024 * 1024 * 2);
  u16* wpt   = (u16*)alloc((size_t)1024 * 1024 * 2);
  u16* phi   = (u16*)alloc((size_t)16384 * 2);
  u16* plo   = (u16*)alloc((size_t)16384 * 2);
  u16* phi_a = (u16*)alloc((size_t)16384 * 2);
  u16* plo_a = (u16*)alloc((size_t)16384 * 2);
  u16* qhi   = (u16*)alloc(NE * 2);
  u16* qlo   = (u16*)alloc(NE * 2);
  u16* khi   = (u16*)alloc(NE * 2);
  u16* klo   = (u16*)alloc(NE * 2);
  u16* vbuf  = (u16*)alloc(NE * 2);
  u16* kvt   = (u16*)alloc((size_t)NBH * 80 * 256 * 2);
  // aliases: x2 dead after v-GEMM (kvpart 42MB <= 64MB); khi dead after k2a (attn 32MB)
  float* kvpart = (float*)x2;
  u16*   attn   = khi;

  split_cast_x2_kernel<<<2048, 256, 0, stream>>>((const float4*)x, x2, (int)(NE / 4));
  split_cast_proj_kernel<<<16, 256, 0, stream>>>(
      (const float4*)proj, (ushort4*)phi, (ushort4*)plo, phi_a, plo_a);
  transpose_wqkv_kernel<<<dim3(96, 32), 256, 0, stream>>>(w_qkv, w2qk, wv);
  transpose_kernel<<<dim3(32, 32), 256, 0, stream>>>(w_proj, wpt);

  // qk: K-doubled single-product GEMM (x2 @ w2qk^T = xhi*w + xlo*w)
  gemm128_kernel<0><<<dim3(128, 16), 256, 0, stream>>>(
      x2, w2qk, 2048, 2048, 2048, qhi, qlo, khi, klo, nullptr, nullptr);
  // v: hi-only, K=1024 (reads hi half of x2)
  gemm128_kernel<1><<<dim3(128, 8), 256, 0, stream>>>(
      x2, wv, 1024, 2048, 1024, vbuf, nullptr, nullptr, nullptr, nullptr, nullptr);

  k2a_kernel<<<dim3(64, KSP), 256, 0, stream>>>(khi, klo, vbuf, phi_a, plo_a, kvpart);
  kv_reduce_kernel<<<dim3(5120), 256, 0, stream>>>(kvpart, kvt);
  k2b_kernel<<<dim3(64, 8), 512, 0, stream>>>(qhi, qlo, kvt, phi, plo, attn);

  gemm128_kernel<2><<<dim3(128, 8), 256, 0, stream>>>(
      attn, wpt, 1024, 1024, 1024,
      nullptr, nullptr, nullptr, nullptr, out, b_proj);
}

// Round 15
// 348.190 us; speedup vs baseline: 1.2118x; 1.2118x over previous
//
#include <hip/hip_runtime.h>

typedef unsigned short u16;
typedef unsigned int u32;
typedef __bf16 bf16x8 __attribute__((ext_vector_type(8)));
typedef float f32x4 __attribute__((ext_vector_type(4)));
typedef u32 u32x4 __attribute__((ext_vector_type(4)));

#define MFMA(a,b,c) __builtin_amdgcn_mfma_f32_16x16x32_bf16((a),(b),(c),0,0,0)

#define BB 4
#define NN 4096
#define DD 1024
#define HH 16
#define HDIM 64
#define RR 256
#define NBH 64
#define KSP 8   // k2a splits

__device__ __forceinline__ float bf2f(u16 h){
  union { u32 u; float f; } c; c.u = ((u32)h) << 16; return c.f;
}
__device__ __forceinline__ u16 f2bf(float f){
  union { float f; u32 u; } c; c.f = f;
  u32 u = c.u;
  return (u16)((u + 0x7FFFu + ((u >> 16) & 1u)) >> 16);
}
__device__ __forceinline__ f32x4 zero4(){ f32x4 v = {0.f,0.f,0.f,0.f}; return v; }

// async global->LDS, 16B per lane; LDS dest = wave-uniform base + lane*16
__device__ __forceinline__ void gload16(const void* g, void* l) {
  __builtin_amdgcn_global_load_lds(
      (const __attribute__((address_space(1))) void*)g,
      (__attribute__((address_space(3))) void*)l, 16, 0, 0);
}

// ---------------- prep kernels ----------------

// x (16384 x 1024 f32) -> x2 (16384 x 2048 bf16): row = [hi | lo]
__global__ void split_cast_x2_kernel(const float4* __restrict__ src, u16* __restrict__ x2, int n4)
{
  int i = blockIdx.x * blockDim.x + threadIdx.x;
  int stride = gridDim.x * blockDim.x;
  for (; i < n4; i += stride) {
    float4 v = src[i];
    int m = i >> 8;          // 256 float4 per 1024-row
    int k4 = (i & 255) * 4;
    ushort4 h, lo;
    h.x = f2bf(v.x); lo.x = f2bf(v.x - bf2f(h.x));
    h.y = f2bf(v.y); lo.y = f2bf(v.y - bf2f(h.y));
    h.z = f2bf(v.z); lo.z = f2bf(v.z - bf2f(h.z));
    h.w = f2bf(v.w); lo.w = f2bf(v.w - bf2f(h.w));
    *(ushort4*)&x2[(size_t)m * 2048 + k4] = h;
    *(ushort4*)&x2[(size_t)m * 2048 + 1024 + k4] = lo;
  }
}

// projection split: natural (for k2b) + row-permuted (for k2a)
// phi_a[32k+8lq+4h+j] = P[32k+16h+4lq+j]  (so kvt columns match k2b's register layout)
__global__ void split_cast_proj_kernel(const float4* __restrict__ src,
                                       ushort4* __restrict__ hi, ushort4* __restrict__ lo,
                                       u16* __restrict__ hia, u16* __restrict__ loa)
{
  int i = blockIdx.x * blockDim.x + threadIdx.x;
  if (i >= 4096) return;   // 16384 elems / 4
  float4 v = src[i];
  ushort4 h, l4;
  h.x = f2bf(v.x); l4.x = f2bf(v.x - bf2f(h.x));
  h.y = f2bf(v.y); l4.y = f2bf(v.y - bf2f(h.y));
  h.z = f2bf(v.z); l4.z = f2bf(v.z - bf2f(h.z));
  h.w = f2bf(v.w); l4.w = f2bf(v.w - bf2f(h.w));
  hi[i] = h;
  lo[i] = l4;
  int prow = i >> 4;          // source row (16 float4 per 64-col row)
  int c4 = (i & 15) * 4;
  int drow = (prow & ~31) | (((prow >> 2) & 3) << 3) | (((prow >> 4) & 1) << 2) | (prow & 3);
  *(ushort4*)&hia[drow * 64 + c4] = h;
  *(ushort4*)&loa[drow * 64 + c4] = l4;
}

// w_qkv (1024 x 3072) -> w2qk (2048 x 2048, row n = [w^T_n | w^T_n]) and wv (1024 x 1024 = w^T v-cols)
__global__ void transpose_wqkv_kernel(const float* __restrict__ src,
                                      u16* __restrict__ w2qk, u16* __restrict__ wv)
{
  __shared__ float T[32][33];
  const int c0 = blockIdx.x * 32, r0 = blockIdx.y * 32;
  const int t = threadIdx.x;
  #pragma unroll
  for (int i = 0; i < 4; ++i) {
    int r = t >> 3, c = (t & 7) + i * 8;
    T[r][c] = src[(size_t)(r0 + r) * 3072 + c0 + c];
  }
  __syncthreads();
  #pragma unroll
  for (int i = 0; i < 4; ++i) {
    int r = t >> 3, c = (t & 7) + i * 8;
    float v = T[c][r];
    int orow = c0 + r, ocol = r0 + c;
    u16 h = f2bf(v);
    if (orow < 2048) {
      w2qk[(size_t)orow * 2048 + ocol] = h;
      w2qk[(size_t)orow * 2048 + 1024 + ocol] = h;
    } else {
      wv[(size_t)(orow - 2048) * 1024 + ocol] = h;
    }
  }
}

// w_proj (1024x1024) -> wpt (transposed bf16)
__global__ void transpose_kernel(const float* __restrict__ src, u16* __restrict__ dst)
{
  __shared__ float T[32][33];
  const int c0 = blockIdx.x * 32, r0 = blockIdx.y * 32;
  const int t = threadIdx.x;
  #pragma unroll
  for (int i = 0; i < 4; ++i) {
    int r = t >> 3, c = (t & 7) + i * 8;
    T[r][c] = src[(size_t)(r0 + r) * 1024 + c0 + c];
  }
  __syncthreads();
  #pragma unroll
  for (int i = 0; i < 4; ++i) {
    int r = t >> 3, c = (t & 7) + i * 8;
    dst[(size_t)(c0 + r) * 1024 + r0 + c] = f2bf(T[c][r]);
  }
}

// ---------------- 256x256 pipelined GEMM (R8/R11-proven 2-phase) ----------------
// A: M x K row-major (stride lda), B: N x K row-major (stride ldb) [i.e. B^T].
// 8 waves (2m x 4n), BK=64, 128 KiB LDS dbuf, counted vmcnt(8), T2 swizzle.
// Measured (R8/R11): qk dispatch 159.5us, 860 TF, MfmaUtil 36.5%, 0 conflicts,
// FETCH 98.7MB. Alternatives all measured WORSE on this problem:
//   fine-phase 8-cluster (R9/R10): 175/168us — extra lockstep drains at 1 blk/CU
//   128^2 BK32 (R13): 185us — FETCH 345MB, L2 panel reuse lost, part HBM-bound
// MODE 0: qk hi/lo scatter (N=2048); MODE 1: v scatter; MODE 2: f32 + bias.
template<int MODE>
__launch_bounds__(512, 2)
__global__ void gemm256_kernel(const u16* __restrict__ A, const u16* __restrict__ B,
                               const int K, const int lda, const int ldb,
                               u16* __restrict__ o0, u16* __restrict__ o1,
                               u16* __restrict__ o2, u16* __restrict__ o3,
                               float* __restrict__ fout, const float* __restrict__ bias)
{
  __shared__ __align__(16) u16 lds[2][2][256 * 64];   // [buf][A/B][row*64+col]
  const int t = threadIdx.x;
  const int w = t >> 6, l = t & 63;
  const int m0 = blockIdx.x * 256, n0 = blockIdx.y * 256;
  const int wm = w & 1, wn = w >> 1;           // 2 x 4 wave grid
  const int lr = l & 15, lq = l >> 4;          // frag row / k-quarter
  const int srow = l >> 3;                     // stage: row within 8-row chunk
  const int gs = ((l & 7) ^ srow) * 8;         // pre-swizzled global col (elems)
  const int swz = lr & 7;                      // read-side row xor

  f32x4 acc[8][4];
  #pragma unroll
  for (int m = 0; m < 8; ++m)
    #pragma unroll
    for (int n = 0; n < 4; ++n) acc[m][n] = zero4();

  const int nt = K / 64;

  auto stage = [&](int kt, int bi) {
    #pragma unroll
    for (int i = 0; i < 4; ++i) {
      const int chunk = w * 4 + i;
      const int row = chunk * 8 + srow;
      gload16(&A[(size_t)(m0 + row) * lda + kt * 64 + gs],
              &lds[bi][0][chunk * 512 + l * 8]);
    }
    #pragma unroll
    for (int i = 0; i < 4; ++i) {
      const int chunk = w * 4 + i;
      const int row = chunk * 8 + srow;
      gload16(&B[(size_t)(n0 + row) * ldb + kt * 64 + gs],
              &lds[bi][1][chunk * 512 + l * 8]);
    }
  };

  stage(0, 0);
  stage(1, 1);
  asm volatile("s_waitcnt vmcnt(8)" ::: "memory");   // tile 0 landed (per wave)
  __builtin_amdgcn_s_barrier();
  __builtin_amdgcn_sched_barrier(0);

  for (int kt = 0; kt < nt; ++kt) {
    const int bi = kt & 1;
    const u16* la = &lds[bi][0][0];
    const u16* lb = &lds[bi][1][0];
    bf16x8 a0[8], b0[4], a1[8], b1[4];
    // ks = 0 frags (swizzled read)
    #pragma unroll
    for (int m = 0; m < 8; ++m)
      a0[m] = *(const bf16x8*)&la[(wm*128 + m*16 + lr)*64 + ((lq ^ swz) * 8)];
    #pragma unroll
    for (int n = 0; n < 4; ++n)
      b0[n] = *(const bf16x8*)&lb[(wn*64 + n*16 + lr)*64 + ((lq ^ swz) * 8)];
    __builtin_amdgcn_s_setprio(1);
    #pragma unroll
    for (int m = 0; m < 8; ++m)
      #pragma unroll
      for (int n = 0; n < 4; ++n)
        acc[m][n] = MFMA(a0[m], b0[n], acc[m][n]);
    __builtin_amdgcn_s_setprio(0);
    // ks = 1 frags
    #pragma unroll
    for (int m = 0; m < 8; ++m)
      a1[m] = *(const bf16x8*)&la[(wm*128 + m*16 + lr)*64 + (((4 + lq) ^ swz) * 8)];
    #pragma unroll
    for (int n = 0; n < 4; ++n)
      b1[n] = *(const bf16x8*)&lb[(wn*64 + n*16 + lr)*64 + (((4 + lq) ^ swz) * 8)];
    asm volatile("s_waitcnt lgkmcnt(0)" ::: "memory");  // all our LDS reads in regs
    __builtin_amdgcn_s_barrier();                       // all waves done reading buf bi
    __builtin_amdgcn_sched_barrier(0);
    if (kt + 2 < nt) stage(kt + 2, bi);                 // refill freed buffer
    __builtin_amdgcn_s_setprio(1);
    #pragma unroll
    for (int m = 0; m < 8; ++m)
      #pragma unroll
      for (int n = 0; n < 4; ++n)
        acc[m][n] = MFMA(a1[m], b1[n], acc[m][n]);      // overlaps stage issue
    __builtin_amdgcn_s_setprio(0);
    if (kt + 2 < nt)      { asm volatile("s_waitcnt vmcnt(8)" ::: "memory"); }
    else if (kt + 1 < nt) { asm volatile("s_waitcnt vmcnt(0)" ::: "memory"); }
    __builtin_amdgcn_s_barrier();                       // tile kt+1 ready for all
    __builtin_amdgcn_sched_barrier(0);
  }

  // epilogue
  #pragma unroll
  for (int m = 0; m < 8; ++m)
    #pragma unroll
    for (int n = 0; n < 4; ++n)
      #pragma unroll
      for (int j = 0; j < 4; ++j) {
        int gm = m0 + wm*128 + m*16 + lq*4 + j;
        int gc = n0 + wn*64 + n*16 + lr;
        float v = acc[m][n][j];
        if (MODE == 2) {
          fout[(size_t)gm * 1024 + gc] = v + bias[gc];
        } else {
          int hh = (gc >> 6) & 15, hd = gc & 63;
          int b = gm >> 12, tok = gm & 4095;
          size_t idx = ((size_t)(b * HH + hh) * NN + tok) * HDIM + hd;
          if (MODE == 0) {
            u16 hi = f2bf(v), lo = f2bf(v - bf2f(hi));
            if ((gc >> 10) == 0) { o0[idx] = hi; o1[idx] = lo; }
            else                 { o2[idx] = hi; o3[idx] = lo; }
          } else {
            o0[idx] = f2bf(v);
          }
        }
      }
}

// ---------------- K2a (R11 v1, measured-best): k features + kv via Kft ----------------
// grid (bh=64, split=KSP), 256 threads. kv_ext = Kf^T @ [V | 1 | 0..] (N=80).
// Uses the PERMUTED projection (phi_a/plo_a) so kvt columns are in k2b's order.
// R12's register-resident variant regressed (-29us): holding pb frags + kvacc +
// facc through the loop cost more than the Kft LDS round-trip saves. Reverted.
__launch_bounds__(256)
__global__ void k2a_kernel(const u16* __restrict__ khi, const u16* __restrict__ klo,
                           const u16* __restrict__ vb,
                           const u16* __restrict__ phi, const u16* __restrict__ plo,
                           float* __restrict__ kvpart)
{
  __shared__ __align__(16) u16 Kh[32*72];
  __shared__ __align__(16) u16 Kl[32*72];
  __shared__ __align__(16) u16 Kft[256*40];
  __shared__ __align__(16) u16 Vt[80*40];
  __shared__ float xnorm[32];
  const int bh = blockIdx.x, sp = blockIdx.y;
  const int t = threadIdx.x, w = t >> 6, l = t & 63;
  const int lr = l & 15, lk = (l >> 4) * 8, l4 = (l >> 4) * 4;
  const size_t base = (size_t)bh * NN * HDIM;
  f32x4 kvacc[4][5];
  #pragma unroll
  for (int i = 0; i < 4; ++i)
    #pragma unroll
    for (int j = 0; j < 5; ++j) kvacc[i][j] = zero4();

  const int TILES = (NN / KSP) / 32;
  for (int tile = 0; tile < TILES; ++tile) {
    const int nb = sp * (NN / KSP) + tile * 32;
    __syncthreads();  // prev iter done reading LDS
    {
      int row = t >> 3, c8 = (t & 7) * 8;
      size_t g = base + (size_t)(nb + row) * HDIM + c8;
      uint4 khv = *(const uint4*)&khi[g];
      uint4 klv = *(const uint4*)&klo[g];
      *(uint4*)&Kh[row*72 + c8] = khv;
      *(uint4*)&Kl[row*72 + c8] = klv;
      uint4 vv = *(const uint4*)&vb[g];
      const u16* pv = (const u16*)&vv;
      #pragma unroll
      for (int j = 0; j < 8; ++j) Vt[(c8 + j)*40 + row] = pv[j];
      if (t < 32) {
        Vt[64*40 + t] = 0x3F80u;  // ones column -> k_sum
        #pragma unroll
        for (int d = 65; d < 80; ++d) Vt[d*40 + t] = 0;
      }
      // parallel xnorm from staging regs: 8 lanes per row
      const u16* ph = (const u16*)&khv;
      const u16* pl = (const u16*)&klv;
      float s = 0.f;
      #pragma unroll
      for (int j = 0; j < 8; ++j) {
        float qv = bf2f(ph[j]) + bf2f(pl[j]);
        s += qv * qv;
      }
      s += __shfl_xor(s, 1);
      s += __shfl_xor(s, 2);
      s += __shfl_xor(s, 4);
      if ((t & 7) == 0) xnorm[row] = 0.5f * s;
    }
    __syncthreads();
    // feature GEMM: M=32 rows, wave w owns r-cols [64w, 64w+64)
    f32x4 facc[2][4];
    #pragma unroll
    for (int i = 0; i < 2; ++i)
      #pragma unroll
      for (int j = 0; j < 4; ++j) facc[i][j] = zero4();
    #pragma unroll
    for (int ks = 0; ks < 2; ++ks) {
      bf16x8 ah[2], al[2];
      #pragma unroll
      for (int fm = 0; fm < 2; ++fm) {
        ah[fm] = *(const bf16x8*)&Kh[(fm*16 + lr)*72 + ks*32 + lk];
        al[fm] = *(const bf16x8*)&Kl[(fm*16 + lr)*72 + ks*32 + lk];
      }
      #pragma unroll
      for (int fn = 0; fn < 4; ++fn) {
        int r = w*64 + fn*16 + lr;
        bf16x8 pbh = *(const bf16x8*)&phi[r*HDIM + ks*32 + lk];
        bf16x8 pbl = *(const bf16x8*)&plo[r*HDIM + ks*32 + lk];
        #pragma unroll
        for (int fm = 0; fm < 2; ++fm) {
          facc[fm][fn] = MFMA(al[fm], pbh, facc[fm][fn]);
          facc[fm][fn] = MFMA(ah[fm], pbl, facc[fm][fn]);
          facc[fm][fn] = MFMA(ah[fm], pbh, facc[fm][fn]);
        }
      }
    }
    #pragma unroll
    for (int fm = 0; fm < 2; ++fm)
      #pragma unroll
      for (int fn = 0; fn < 4; ++fn)
        #pragma unroll
        for (int j = 0; j < 4; ++j) {
          int row = fm*16 + l4 + j;          // n local
          int r = w*64 + fn*16 + lr;
          float e = __expf(facc[fm][fn][j] - xnorm[row]) * 0.0625f + 1e-6f;
          Kft[r*40 + row] = f2bf(e);
        }
    __syncthreads();
    // kv accumulate: wave w owns r-rows [64w, 64w+64), K=32 (this tile)
    {
      bf16x8 bv[5];
      #pragma unroll
      for (int fn = 0; fn < 5; ++fn)
        bv[fn] = *(const bf16x8*)&Vt[(fn*16 + lr)*40 + lk];
      #pragma unroll
      for (int fr = 0; fr < 4; ++fr) {
        bf16x8 a = *(const bf16x8*)&Kft[(w*64 + fr*16 + lr)*40 + lk];
        #pragma unroll
        for (int fn = 0; fn < 5; ++fn) kvacc[fr][fn] = MFMA(a, bv[fn], kvacc[fr][fn]);
      }
    }
  }
  // kvpart[bh][sp][d][r]
  #pragma unroll
  for (int fr = 0; fr < 4; ++fr)
    #pragma unroll
    for (int fn = 0; fn < 5; ++fn)
      #pragma unroll
      for (int j = 0; j < 4; ++j) {
        int r = w*64 + fr*16 + l4 + j;
        int d = fn*16 + lr;
        kvpart[(((size_t)bh*KSP + sp)*80 + d)*256 + r] = kvacc[fr][fn][j];
      }
}

__global__ void kv_reduce_kernel(const float* __restrict__ kvpart, u16* __restrict__ kvt)
{
  int i = blockIdx.x * 256 + threadIdx.x;
  if (i >= NBH * 80 * 256) return;
  int bh = i / (80 * 256), rem = i - bh * (80 * 256);
  float s = 0.f;
  #pragma unroll
  for (int sp = 0; sp < KSP; ++sp)
    s += kvpart[((size_t)bh*KSP + sp)*80*256 + rem];
  kvt[i] = f2bf(s);  // kvt[bh][d][r], d<64: kv^T; d==64: k_sum
}

// ---------------- K2b v7: fused per-slot feature+PV, PINNED schedule ----------------
// Same algebra/layout as v6 (all operands LDS-staged). The slot loop and tile
// loop are NOT unrolled and each slot ends with sched_barrier(0): full unroll
// exposed 96 independent loads, scheduler hoisted them, regalloc spilled ~220
// dwords/lane (R4-R7's ~650MB excess traffic). Pinning fixed it (R8: -77µs).
__launch_bounds__(512, 2)
__global__ void k2b_kernel(const u16* __restrict__ qhi, const u16* __restrict__ qlo,
                           const u16* __restrict__ kvt,
                           const u16* __restrict__ phi, const u16* __restrict__ plo,
                           u16* __restrict__ attn)
{
  __shared__ __align__(16) u16 KV[80*256];    // [d][r] 512B rows; 16B-blk ^= d&7
  __shared__ __align__(16) u16 PH[256*64];    // [fr][d] 128B rows; 16B-blk ^= fr&7
  __shared__ __align__(16) u16 PL[256*64];
  const int bh = blockIdx.x, b = bh >> 4, h = bh & 15;
  const int c0 = blockIdx.y * 512;
  const int t = threadIdx.x, w = t >> 6, l = t & 63;
  const int lr = l & 15, lq = l >> 4;
  const size_t base = (size_t)bh * NN * HDIM;

  // stage kv_ext (80x256) + projection (256x64 hi/lo), both-sides swizzle
  {
    const uint4* kvg = (const uint4*)(kvt + (size_t)bh * 80 * 256);
    #pragma unroll
    for (int i = 0; i < 5; ++i) {
      int idx = t + i * 512;
      int d = idx >> 5, rb = idx & 31;
      *(uint4*)((char*)KV + d * 512 + ((rb ^ (d & 7)) << 4)) = kvg[idx];
    }
    const uint4* pg = (const uint4*)phi;
    const uint4* lg = (const uint4*)plo;
    #pragma unroll
    for (int i = 0; i < 4; ++i) {
      int idx = t + i * 512;
      int fr = idx >> 3, sl = idx & 7;
      int off = fr * 128 + (((sl ^ (fr & 7))) << 4);
      *(uint4*)((char*)PH + off) = pg[idx];
      *(uint4*)((char*)PL + off) = lg[idx];
    }
  }
  __syncthreads();

  const int swl = (lr & 7) << 4;       // projection read-side row xor (bytes)
  #pragma unroll 1
  for (int tile = 0; tile < 4; ++tile) {
    const int r0 = c0 + tile * 128 + w * 16;
    // Q frags (B-operand: col=lr -> q-row = r0+lr, k = d = half*32 + lq*8 + e)
    bf16x8 ah0, ah1, al0, al1;
    {
      size_t g = base + (size_t)(r0 + lr) * HDIM + lq*8;
      ah0 = *(const bf16x8*)&qhi[g];
      al0 = *(const bf16x8*)&qlo[g];
      ah1 = *(const bf16x8*)&qhi[g + 32];
      al1 = *(const bf16x8*)&qlo[g + 32];
    }
    // xnorm for q-row r0+lr: per-lane partial over d, reduce across lq groups
    float s = 0.f;
    #pragma unroll
    for (int e = 0; e < 8; ++e) {
      float q0 = (float)ah0[e] + (float)al0[e];
      float q1 = (float)ah1[e] + (float)al1[e];
      s += q0 * q0 + q1 * q1;
    }
    s += __shfl_xor(s, 16);
    s += __shfl_xor(s, 32);
    const float xn = 0.5f * s;

    f32x4 oa0 = zero4(), oa1 = zero4(), oa2 = zero4(), oa3 = zero4(), oa4 = zero4();

    // fused slots: feature frags fn=2i,2i+1 -> exp -> PV slot i.
    // NOT unrolled + sched_barrier: loads of slot i+1 cannot be hoisted into slot i.
    #pragma unroll 1
    for (int i = 0; i < 8; ++i) {
      f32x4 f0 = zero4(), f1 = zero4();
      {
        const int ro0 = (32*i + lr) * 128;     // PH/PL byte row for fn=2i
        const int ro1 = ro0 + 2048;            // fn=2i+1 (+16 rows)
        const int cb0 = (lq*16) ^ swl;         // k-half 0 (cols 0..31)
        const int cb1 = (64 + lq*16) ^ swl;    // k-half 1 (cols 32..63)
        bf16x8 v;
        v = *(const bf16x8*)((const char*)PH + ro0 + cb0);
        f0 = MFMA(v, ah0, f0); f0 = MFMA(v, al0, f0);
        v = *(const bf16x8*)((const char*)PL + ro0 + cb0);
        f0 = MFMA(v, ah0, f0);
        v = *(const bf16x8*)((const char*)PH + ro0 + cb1);
        f0 = MFMA(v, ah1, f0); f0 = MFMA(v, al1, f0);
        v = *(const bf16x8*)((const char*)PL + ro0 + cb1);
        f0 = MFMA(v, ah1, f0);
        v = *(const bf16x8*)((const char*)PH + ro1 + cb0);
        f1 = MFMA(v, ah0, f1); f1 = MFMA(v, al0, f1);
        v = *(const bf16x8*)((const char*)PL + ro1 + cb0);
        f1 = MFMA(v, ah0, f1);
        v = *(const bf16x8*)((const char*)PH + ro1 + cb1);
        f1 = MFMA(v, ah1, f1); f1 = MFMA(v, al1, f1);
        v = *(const bf16x8*)((const char*)PL + ro1 + cb1);
        f1 = MFMA(v, ah1, f1);
      }
      // exp + pack -> PV A-frag (k = i*32 + lq*8 + e), register-only value
      u32x4 aw;
      aw.x = (u32)f2bf(__expf(f0[0] - xn) * 0.0625f + 1e-6f)
           | ((u32)f2bf(__expf(f0[1] - xn) * 0.0625f + 1e-6f) << 16);
      aw.y = (u32)f2bf(__expf(f0[2] - xn) * 0.0625f + 1e-6f)
           | ((u32)f2bf(__expf(f0[3] - xn) * 0.0625f + 1e-6f) << 16);
      aw.z = (u32)f2bf(__expf(f1[0] - xn) * 0.0625f + 1e-6f)
           | ((u32)f2bf(__expf(f1[1] - xn) * 0.0625f + 1e-6f) << 16);
      aw.w = (u32)f2bf(__expf(f1[2] - xn) * 0.0625f + 1e-6f)
           | ((u32)f2bf(__expf(f1[3] - xn) * 0.0625f + 1e-6f) << 16);
      bf16x8 a = __builtin_bit_cast(bf16x8, aw);
      // PV: KV rows d=fn*16+lr; (d&7)==(lr&7) for all fn
      const int kvsw = (((i << 2) | lq) ^ (lr & 7)) << 4;
      oa0 = MFMA(a, *(const bf16x8*)((const char*)KV + (0*16+lr)*512 + kvsw), oa0);
      oa1 = MFMA(a, *(const bf16x8*)((const char*)KV + (1*16+lr)*512 + kvsw), oa1);
      oa2 = MFMA(a, *(const bf16x8*)((const char*)KV + (2*16+lr)*512 + kvsw), oa2);
      oa3 = MFMA(a, *(const bf16x8*)((const char*)KV + (3*16+lr)*512 + kvsw), oa3);
      oa4 = MFMA(a, *(const bf16x8*)((const char*)KV + (4*16+lr)*512 + kvsw), oa4);
      __builtin_amdgcn_sched_barrier(0);   // pin: no cross-slot motion
    }
    // normalize (denom = col 64 -> lane lr==0 within each lq) + store
    #pragma unroll
    for (int j = 0; j < 4; ++j) {
      float dn = __shfl(oa4[j], l & 48) + 1e-6f;
      float inv = 1.0f / dn;
      int q = r0 + lq*4 + j;
      u16* arow = attn + ((size_t)b * NN + q) * DD + h * HDIM + lr;
      arow[0]  = f2bf(oa0[j] * inv);
      arow[16] = f2bf(oa1[j] * inv);
      arow[32] = f2bf(oa2[j] * inv);
      arow[48] = f2bf(oa3[j] * inv);
    }
  }
}

// ---------------- host ----------------

extern "C" void kernel_launch(void* const* d_in, const int* in_sizes, int n_in,
                              void* d_out, int out_size, void* d_ws, size_t ws_size,
                              hipStream_t stream)
{
  const float* x      = (const float*)d_in[0];
  const float* w_qkv  = (const float*)d_in[1];
  const float* w_proj = (const float*)d_in[2];
  const float* b_proj = (const float*)d_in[3];
  const float* proj   = (const float*)d_in[4];
  float* out = (float*)d_out;

  char* p = (char*)d_ws;
  auto alloc = [&](size_t nbytes) {
    char* r = p; p += (nbytes + 255) & ~(size_t)255; return r;
  };
  const size_t NE = (size_t)16777216;  // B*N*D elements
  u16* x2    = (u16*)alloc(NE * 2 * 2);                 // 16384 x 2048 (hi|lo)
  u16* w2qk  = (u16*)alloc((size_t)2048 * 2048 * 2);    // duplicated qk weights
  u16* wv    = (u16*)alloc((size_t)1024 * 1024 * 2);
  u16* wpt   = (u16*)alloc((size_t)1024 * 1024 * 2);
  u16* phi   = (u16*)alloc((size_t)16384 * 2);
  u16* plo   = (u16*)alloc((size_t)16384 * 2);
  u16* phi_a = (u16*)alloc((size_t)16384 * 2);
  u16* plo_a = (u16*)alloc((size_t)16384 * 2);
  u16* qhi   = (u16*)alloc(NE * 2);
  u16* qlo   = (u16*)alloc(NE * 2);
  u16* khi   = (u16*)alloc(NE * 2);
  u16* klo   = (u16*)alloc(NE * 2);
  u16* vbuf  = (u16*)alloc(NE * 2);
  u16* kvt   = (u16*)alloc((size_t)NBH * 80 * 256 * 2);
  // aliases: x2 dead after v-GEMM (kvpart 42MB <= 64MB); khi dead after k2a (attn 32MB)
  float* kvpart = (float*)x2;
  u16*   attn   = khi;

  split_cast_x2_kernel<<<2048, 256, 0, stream>>>((const float4*)x, x2, (int)(NE / 4));
  split_cast_proj_kernel<<<16, 256, 0, stream>>>(
      (const float4*)proj, (ushort4*)phi, (ushort4*)plo, phi_a, plo_a);
  transpose_wqkv_kernel<<<dim3(96, 32), 256, 0, stream>>>(w_qkv, w2qk, wv);
  transpose_kernel<<<dim3(32, 32), 256, 0, stream>>>(w_proj, wpt);

  // qk: K-doubled single-product GEMM (x2 @ w2qk^T = xhi*w + xlo*w)
  gemm256_kernel<0><<<dim3(64, 8), 512, 0, stream>>>(
      x2, w2qk, 2048, 2048, 2048, qhi, qlo, khi, klo, nullptr, nullptr);
  // v: hi-only, K=1024 (reads hi half of x2)
  gemm256_kernel<1><<<dim3(64, 4), 512, 0, stream>>>(
      x2, wv, 1024, 2048, 1024, vbuf, nullptr, nullptr, nullptr, nullptr, nullptr);

  k2a_kernel<<<dim3(64, KSP), 256, 0, stream>>>(khi, klo, vbuf, phi_a, plo_a, kvpart);
  kv_reduce_kernel<<<dim3(5120), 256, 0, stream>>>(kvpart, kvt);
  k2b_kernel<<<dim3(64, 8), 512, 0, stream>>>(qhi, qlo, kvt, phi, plo, attn);

  gemm256_kernel<2><<<dim3(64, 4), 512, 0, stream>>>(
      attn, wpt, 1024, 1024, 1024,
      nullptr, nullptr, nullptr, nullptr, out, b_proj);
}